// Round 8
// baseline (1150.438 us; speedup 1.0000x reference)
//
#include <hip/hip_runtime.h>
#include <math.h>

#define TS 256
#define BB 1024
#define NQ 8
#define INDIM 128
#define CATDIM 136

typedef float v2f __attribute__((ext_vector_type(2)));

__device__ __forceinline__ float dpp_xor1(float v) {
    return __int_as_float(__builtin_amdgcn_mov_dpp(__float_as_int(v), 0xB1, 0xF, 0xF, true));
}
__device__ __forceinline__ float dpp_xor2(float v) {
    return __int_as_float(__builtin_amdgcn_mov_dpp(__float_as_int(v), 0x4E, 0xF, 0xF, true));
}
__device__ __forceinline__ float dpp_xor8(float v) {   // row_ror:8 within 16-lane row == lane^8
    return __int_as_float(__builtin_amdgcn_mov_dpp(__float_as_int(v), 0x128, 0xF, 0xF, true));
}
__device__ __forceinline__ float rdlane(float v, int l) {
    return __int_as_float(__builtin_amdgcn_readlane(__float_as_int(v), l));
}
__device__ __forceinline__ v2f mk2(float x, float y) { v2f r; r.x = x; r.y = y; return r; }

// ---- packed dual-FP32 (VOP3P) helpers ----
__device__ __forceinline__ v2f pk_mul(v2f a, v2f b) {
    v2f d; asm("v_pk_mul_f32 %0, %1, %2" : "=v"(d) : "v"(a), "v"(b)); return d;
}
__device__ __forceinline__ v2f pk_fma(v2f a, v2f b, v2f c) {
    v2f d; asm("v_pk_fma_f32 %0, %1, %2, %3" : "=v"(d) : "v"(a), "v"(b), "v"(c)); return d;
}
// d = a*b - c
__device__ __forceinline__ v2f pk_fma_negc(v2f a, v2f b, v2f c) {
    v2f d; asm("v_pk_fma_f32 %0, %1, %2, %3 neg_lo:[0,0,1] neg_hi:[0,0,1]"
               : "=v"(d) : "v"(a), "v"(b), "v"(c)); return d;
}
// t = (a.lo*b.lo, a.hi*b.lo)
__device__ __forceinline__ v2f pk_mul_t(v2f a, v2f b) {
    v2f d; asm("v_pk_mul_f32 %0, %1, %2 op_sel_hi:[1,0]" : "=v"(d) : "v"(a), "v"(b)); return d;
}
// d.lo = -a.hi*b.hi + t.lo ; d.hi = a.lo*b.hi + t.hi
__device__ __forceinline__ v2f pk_fma_cmul(v2f a, v2f b, v2f t) {
    v2f d; asm("v_pk_fma_f32 %0, %1, %2, %3 op_sel:[1,1,0] op_sel_hi:[0,1,1] neg_lo:[0,1,0]"
               : "=v"(d) : "v"(a), "v"(b), "v"(t)); return d;
}
__device__ __forceinline__ v2f cmul(v2f a, v2f b) { return pk_fma_cmul(a, b, pk_mul_t(a, b)); }

// ============ Kernel 1: xproj[b][t][g*8+q] = x[t][b]·W_g[q][:128] + bias_g[q] ============
__launch_bounds__(256)
__global__ void qlstm_xproj(const float* __restrict__ x,
    const float* __restrict__ Wf, const float* __restrict__ bf,
    const float* __restrict__ Wi, const float* __restrict__ bi,
    const float* __restrict__ Wg, const float* __restrict__ bg,
    const float* __restrict__ Wo, const float* __restrict__ bo,
    float* __restrict__ xproj)
{
    const int b = blockIdx.x;
    const int wv = threadIdx.x >> 6;
    const int lane = threadIdx.x & 63;
    const int q = lane >> 3;
    const int kg = lane & 7;

    const float* Ws[4] = { Wf, Wi, Wg, Wo };
    const float* bs[4] = { bf, bi, bg, bo };
    float4 wfrag[4][4];
    float bias_w[4];
    #pragma unroll
    for (int g = 0; g < 4; ++g) {
        const float* Wq = Ws[g] + q * CATDIM + kg * 16;
        #pragma unroll
        for (int c4 = 0; c4 < 4; ++c4) wfrag[g][c4] = *(const float4*)(Wq + c4 * 4);
        bias_w[g] = bs[g][q];
    }

    for (int t = wv; t < TS; t += 4) {
        const float* xr = x + ((size_t)t * BB + b) * INDIM + kg * 16;
        float4 x0 = *(const float4*)(xr);
        float4 x1 = *(const float4*)(xr + 4);
        float4 x2 = *(const float4*)(xr + 8);
        float4 x3 = *(const float4*)(xr + 12);
        float* outrow = xproj + ((size_t)b * TS + t) * 32;
        #pragma unroll
        for (int g = 0; g < 4; ++g) {
            float p =
                x0.x*wfrag[g][0].x + x0.y*wfrag[g][0].y + x0.z*wfrag[g][0].z + x0.w*wfrag[g][0].w +
                x1.x*wfrag[g][1].x + x1.y*wfrag[g][1].y + x1.z*wfrag[g][1].z + x1.w*wfrag[g][1].w +
                x2.x*wfrag[g][2].x + x2.y*wfrag[g][2].y + x2.z*wfrag[g][2].z + x2.w*wfrag[g][2].w +
                x3.x*wfrag[g][3].x + x3.y*wfrag[g][3].y + x3.z*wfrag[g][3].z + x3.w*wfrag[g][3].w;
            p += dpp_xor1(p);
            p += dpp_xor2(p);
            p += __shfl_xor(p, 4, 64);
            if (kg == 0) outrow[g * 8 + q] = p + bias_w[g];
        }
    }
}

// ============ Kernel 2: one WAVE = one batch element; all 4 gates in-wave ============
// No barriers anywhere. Lane holds amps k=j*64+lane; per gate, post-reduction
// every lane holds S_g[q(lane)] with q(lane)=4*l0+2*l1+l2 -> LSTM is lane-local.
__launch_bounds__(64, 1)
__global__ void qlstm_rec(const float* __restrict__ xproj,
    const float* __restrict__ Wf, const float* __restrict__ Pf,
    const float* __restrict__ Wi, const float* __restrict__ Pi,
    const float* __restrict__ Wg, const float* __restrict__ Pg,
    const float* __restrict__ Wo, const float* __restrict__ Po,
    float* __restrict__ out, float* __restrict__ hst, float* __restrict__ cst)
{
    const int b = blockIdx.x;
    const int lane = threadIdx.x;
    const int q = lane >> 3;

    __shared__ float xplds[TS * 32];      // 32 KB

    // ---- stage this element's angle bases (same wave reads later; no barrier) ----
    {
        const float4* s4 = (const float4*)(xproj + (size_t)b * (TS * 32));
        float4* d4 = (float4*)xplds;
        #pragma unroll
        for (int i = 0; i < 32; ++i) d4[lane + i * 64] = s4[lane + i * 64];
    }

    const float* Ws[4] = { Wf, Wi, Wg, Wo };
    const float* Ps[4] = { Pf, Pi, Pg, Po };

    // ---- lane bits / gray-code selectors / measurement signs (shared) ----
    const int l0 = lane & 1, l1 = (lane >> 1) & 1, l2b = (lane >> 2) & 1;
    const int l3 = (lane >> 3) & 1, l4 = (lane >> 4) & 1, l5 = (lane >> 5) & 1;
    const int s0 = l0 ^ l1, s1 = l1 ^ l2b, s2 = l2b ^ l3, s3 = l3 ^ l4, s4 = l4 ^ l5;
    int pr_ = l5;            const float sg2 = pr_ ? -1.f : 1.f;
    pr_ ^= l4;               const float sg3 = pr_ ? -1.f : 1.f;
    pr_ ^= l3;               const float sg4 = pr_ ? -1.f : 1.f;
    pr_ ^= l2b;              const float sg5 = pr_ ? -1.f : 1.f;
    pr_ ^= l1;               const float sg6 = pr_ ? -1.f : 1.f;
    pr_ ^= l0;               const float sg7 = pr_ ? -1.f : 1.f;

    // ---- per-gate constants ----
    v2f whp[4][4];                       // h weights (packed pairs)
    v2f uw7[4], uw6[4], uw5[4], uw4[4], uw3[4], uwga[4], uwgb[4];
    float c00[4], s00[4], c01[4], s01[4];
    v2f cppA[4], sppA[4], cppB[4], sppB[4];   // RY1 wires 0,1 packed consts
    v2f cppk[4][6], svpk[4][6];               // RY1 wires 2..7
    #pragma unroll
    for (int g = 0; g < 4; ++g) {
        const float* P = Ps[g];
        float cp0[8], sp0[8], cp1[8], sp1[8];
        #pragma unroll
        for (int qq = 0; qq < 8; ++qq) {
            float h0 = 0.5f * P[qq];
            cp0[qq] = cosf(h0); sp0[qq] = sinf(h0);
            float h1 = 0.5f * P[8 + qq];
            cp1[qq] = cosf(h1); sp1[qq] = sinf(h1);
        }
        uw7[g]  = mk2(s0 ? sp0[7] : cp0[7], s0 ? -cp0[7] : sp0[7]);
        uw6[g]  = mk2(s1 ? sp0[6] : cp0[6], s1 ? -cp0[6] : sp0[6]);
        uw5[g]  = mk2(s2 ? sp0[5] : cp0[5], s2 ? -cp0[5] : sp0[5]);
        uw4[g]  = mk2(s3 ? sp0[4] : cp0[4], s3 ? -cp0[4] : sp0[4]);
        uw3[g]  = mk2(s4 ? sp0[3] : cp0[3], s4 ? -cp0[3] : sp0[3]);
        uwga[g] = mk2(l5 ? sp0[2] : cp0[2], l5 ? -cp0[2] : sp0[2]);
        uwgb[g] = mk2(l5 ? cp0[2] : sp0[2], l5 ? sp0[2] : -cp0[2]);
        c00[g] = cp0[0]; s00[g] = sp0[0]; c01[g] = cp0[1]; s01[g] = sp0[1];
        cppA[g] = mk2(cp1[0], cp1[0]); sppA[g] = mk2(sp1[0], sp1[0]);
        cppB[g] = mk2(cp1[1], cp1[1]); sppB[g] = mk2(sp1[1], sp1[1]);
        const int lb[6] = { l5, l4, l3, l2b, l1, l0 };
        #pragma unroll
        for (int k = 0; k < 6; ++k) {
            float cp = cp1[2 + k];
            float sv = lb[k] ? sp1[2 + k] : -sp1[2 + k];
            cppk[g][k] = mk2(cp, cp);
            svpk[g][k] = mk2(sv, sv);
        }
        const float* Wq = Ws[g] + q * CATDIM;
        #pragma unroll
        for (int j = 0; j < 4; ++j)
            whp[g][j] = mk2(Wq[INDIM + 2*j], Wq[INDIM + 2*j + 1]);
    }

    // ---- LSTM state: lane-local cell for qubit q(lane); h broadcast scalars ----
    float c_reg = 0.f, hv = 0.f;
    float hs0 = 0.f, hs1 = 0.f, hs2 = 0.f, hs3 = 0.f;
    float hs4 = 0.f, hs5 = 0.f, hs6 = 0.f, hs7 = 0.f;

    float xb[4];
    #pragma unroll
    for (int g = 0; g < 4; ++g) xb[g] = xplds[g * 8 + q];

    for (int t = 0; t < TS; ++t) {
        // ---- angles + sincos for all 4 gates ----
        float co[4], so[4];
        #pragma unroll
        for (int g = 0; g < 4; ++g) {
            v2f hacc = pk_fma(mk2(hs2, hs3), whp[g][1], pk_mul(mk2(hs0, hs1), whp[g][0]));
            hacc = pk_fma(mk2(hs4, hs5), whp[g][2], hacc);
            hacc = pk_fma(mk2(hs6, hs7), whp[g][3], hacc);
            float ang = xb[g] + hacc.x + hacc.y;
            __sincosf(0.5f * ang, &so[g], &co[g]);
        }

        // prefetch next step's angle bases (off critical path)
        {
            int tn = (t + 1 < TS) ? t + 1 : t;
            #pragma unroll
            for (int g = 0; g < 4; ++g) xb[g] = xplds[tn * 32 + g * 8 + q];
        }

        // ---- per-gate circuit ----
        float vres[4];
        #pragma unroll
        for (int g = 0; g < 4; ++g) {
            float cqs[8], sqs[8];
            #pragma unroll
            for (int qq = 0; qq < 8; ++qq) {
                cqs[qq] = rdlane(co[g], qq * 8);
                sqs[qq] = rdlane(so[g], qq * 8);
            }
            // product state build (gray-code fold), tree-associated
            v2f f7 = mk2(uw7[g].x * cqs[7], uw7[g].y * sqs[7]);
            v2f f6 = mk2(uw6[g].x * cqs[6], uw6[g].y * sqs[6]);
            v2f f5 = mk2(uw5[g].x * cqs[5], uw5[g].y * sqs[5]);
            v2f f4 = mk2(uw4[g].x * cqs[4], uw4[g].y * sqs[4]);
            v2f f3 = mk2(uw3[g].x * cqs[3], uw3[g].y * sqs[3]);
            v2f t76 = cmul(f7, f6);
            v2f t54 = cmul(f5, f4);
            v2f M = cmul(cmul(t76, t54), f3);
            v2f MGa = cmul(M, mk2(uwga[g].x * cqs[2], uwga[g].y * sqs[2]));
            v2f MGb = cmul(M, mk2(uwgb[g].x * cqs[2], uwgb[g].y * sqs[2]));
            v2f a1 = mk2(c01[g] * cqs[1], s01[g] * sqs[1]);
            v2f b1 = mk2(s01[g] * cqs[1], -(c01[g] * sqs[1]));
            v2f a0 = mk2(c00[g] * cqs[0], s00[g] * sqs[0]);
            v2f b0 = mk2(s00[g] * cqs[0], -(c00[g] * sqs[0]));
            v2f z0 = cmul(MGa, cmul(a1, a0));
            v2f z1 = cmul(MGb, cmul(b1, a0));
            v2f z2 = cmul(MGa, cmul(b1, b0));
            v2f z3 = cmul(MGb, cmul(a1, b0));

            // RY1 wire0 (bit7): pairs (z0,z2),(z1,z3)  [packed]
            {
                v2f t0 = z0, t1 = z1;
                z0 = pk_fma_negc(t0, cppA[g], pk_mul(z2, sppA[g]));
                z2 = pk_fma(z2, cppA[g], pk_mul(t0, sppA[g]));
                z1 = pk_fma_negc(t1, cppA[g], pk_mul(z3, sppA[g]));
                z3 = pk_fma(z3, cppA[g], pk_mul(t1, sppA[g]));
            }
            // RY1 wire1 (bit6): pairs (z0,z1),(z2,z3)  [packed]
            {
                v2f t0 = z0, t2 = z2;
                z0 = pk_fma_negc(t0, cppB[g], pk_mul(z1, sppB[g]));
                z1 = pk_fma(z1, cppB[g], pk_mul(t0, sppB[g]));
                z2 = pk_fma_negc(t2, cppB[g], pk_mul(z3, sppB[g]));
                z3 = pk_fma(z3, cppB[g], pk_mul(t2, sppB[g]));
            }
            // RY1 wires 2..7
            #define RYP(SHUF, CPP, SVP) {                               \
                v2f p_;                                                 \
                p_.x = SHUF(z0.x); p_.y = SHUF(z0.y);                   \
                z0 = pk_fma(z0, CPP, pk_mul(p_, SVP));                  \
                p_.x = SHUF(z1.x); p_.y = SHUF(z1.y);                   \
                z1 = pk_fma(z1, CPP, pk_mul(p_, SVP));                  \
                p_.x = SHUF(z2.x); p_.y = SHUF(z2.y);                   \
                z2 = pk_fma(z2, CPP, pk_mul(p_, SVP));                  \
                p_.x = SHUF(z3.x); p_.y = SHUF(z3.y);                   \
                z3 = pk_fma(z3, CPP, pk_mul(p_, SVP));                  \
            }
            #define SH32(v) __shfl_xor(v, 32, 64)
            #define SH16(v) __shfl_xor(v, 16, 64)
            #define SH4(v)  __shfl_xor(v, 4, 64)
            RYP(SH32, cppk[g][0], svpk[g][0])      // wire2 (bit5)  [DS]
            RYP(SH16, cppk[g][1], svpk[g][1])      // wire3 (bit4)  [DS]
            RYP(dpp_xor8, cppk[g][2], svpk[g][2])  // wire4 (bit3)  [DPP]
            RYP(SH4,  cppk[g][3], svpk[g][3])      // wire5 (bit2)  [DS]
            RYP(dpp_xor2, cppk[g][4], svpk[g][4])  // wire6 (bit1)  [DPP]
            RYP(dpp_xor1, cppk[g][5], svpk[g][5])  // wire7 (bit0)  [DPP]

            // measurement (CNOT#2 folded into signs)
            v2f q0 = pk_mul(z0, z0), q1 = pk_mul(z1, z1);
            v2f q2 = pk_mul(z2, z2), q3 = pk_mul(z3, z3);
            float p0 = q0.x + q0.y, p1 = q1.x + q1.y;
            float p2 = q2.x + q2.y, p3 = q3.x + q3.y;
            float v0 = (p0 + p1) - (p2 + p3);
            float D  = (p0 - p1) - (p2 - p3);
            float v1 = D;
            float v2 = sg2 * D;
            float v3 = sg3 * D;
            float v4 = sg4 * D;
            float v5 = sg5 * D;
            float v6 = sg6 * D;
            float v7 = sg7 * D;

            // 8-value 64-lane reduction
            {
                int c0 = lane & 1;
                float s, r;
                s = c0 ? v0 : v4; r = dpp_xor1(s); v0 = (c0 ? v4 : v0) + r;
                s = c0 ? v1 : v5; r = dpp_xor1(s); v1 = (c0 ? v5 : v1) + r;
                s = c0 ? v2 : v6; r = dpp_xor1(s); v2 = (c0 ? v6 : v2) + r;
                s = c0 ? v3 : v7; r = dpp_xor1(s); v3 = (c0 ? v7 : v3) + r;
                int c1 = lane & 2;
                s = c1 ? v0 : v2; r = dpp_xor2(s); v0 = (c1 ? v2 : v0) + r;
                s = c1 ? v1 : v3; r = dpp_xor2(s); v1 = (c1 ? v3 : v1) + r;
                int c2 = lane & 4;
                s = c2 ? v0 : v1; r = __shfl_xor(s, 4, 64); v0 = (c2 ? v1 : v0) + r;
                v0 += dpp_xor8(v0);
                v0 += __shfl_xor(v0, 16, 64);
                v0 += __shfl_xor(v0, 32, 64);
            }
            vres[g] = v0;   // every lane: S_g[q], q = 4*l0 + 2*l1 + l2
        }

        // ---- lane-local LSTM update (no barrier, no LDS) ----
        float fv = 1.f / (1.f + __expf(-vres[0]));
        float iv = 1.f / (1.f + __expf(-vres[1]));
        float e2g = __expf(2.f * vres[2]);
        float gv = (e2g - 1.f) / (e2g + 1.f);
        float ov = 1.f / (1.f + __expf(-vres[3]));
        c_reg = fv * c_reg + iv * gv;
        float e2c = __expf(2.f * c_reg);
        hv = ov * ((e2c - 1.f) / (e2c + 1.f));

        if (lane < 8) {
            int q8 = ((lane & 1) << 2) | (lane & 2) | ((lane >> 2) & 1);
            out[((size_t)t * BB + b) * NQ + q8] = hv;
        }

        // broadcast h: lane holding qubit j is bitrev3(j)
        hs0 = rdlane(hv, 0); hs1 = rdlane(hv, 4);
        hs2 = rdlane(hv, 2); hs3 = rdlane(hv, 6);
        hs4 = rdlane(hv, 1); hs5 = rdlane(hv, 5);
        hs6 = rdlane(hv, 3); hs7 = rdlane(hv, 7);
    }

    if (lane < 8) {
        int q8 = ((lane & 1) << 2) | (lane & 2) | ((lane >> 2) & 1);
        hst[b * NQ + q8] = hv;
        cst[b * NQ + q8] = c_reg;
    }
}

extern "C" void kernel_launch(void* const* d_in, const int* in_sizes, int n_in,
                              void* d_out, int out_size, void* d_ws, size_t ws_size,
                              hipStream_t stream) {
    const float* x  = (const float*)d_in[0];
    const float* Wf = (const float*)d_in[1];
    const float* bf = (const float*)d_in[2];
    const float* Pf = (const float*)d_in[3];
    const float* Wi = (const float*)d_in[4];
    const float* bi = (const float*)d_in[5];
    const float* Pi = (const float*)d_in[6];
    const float* Wg = (const float*)d_in[7];
    const float* bg = (const float*)d_in[8];
    const float* Pg = (const float*)d_in[9];
    const float* Wo = (const float*)d_in[10];
    const float* bo = (const float*)d_in[11];
    const float* Po = (const float*)d_in[12];

    float* out = (float*)d_out;
    float* hst = out + (size_t)TS * BB * NQ;
    float* cst = hst + (size_t)BB * NQ;
    float* xproj = (float*)d_ws;             // TS*BB*32 floats = 33.5 MB scratch

    qlstm_xproj<<<BB, 256, 0, stream>>>(x, Wf, bf, Wi, bi, Wg, bg, Wo, bo, xproj);
    qlstm_rec<<<BB, 64, 0, stream>>>(xproj, Wf, Pf, Wi, Pi, Wg, Pg, Wo, Po,
                                     out, hst, cst);
}

// Round 9
// 358.016 us; speedup vs baseline: 3.2134x; 3.2134x over previous
//
#include <hip/hip_runtime.h>
#include <math.h>

#define TS 256
#define BB 1024
#define NQ 8
#define INDIM 128
#define CATDIM 136

typedef float v2f __attribute__((ext_vector_type(2)));

__device__ __forceinline__ float dpp_xor1(float v) {
    return __int_as_float(__builtin_amdgcn_mov_dpp(__float_as_int(v), 0xB1, 0xF, 0xF, true));
}
__device__ __forceinline__ float dpp_xor2(float v) {
    return __int_as_float(__builtin_amdgcn_mov_dpp(__float_as_int(v), 0x4E, 0xF, 0xF, true));
}
__device__ __forceinline__ float dpp_q0(float v) {   // quad broadcast lane0
    return __int_as_float(__builtin_amdgcn_mov_dpp(__float_as_int(v), 0x00, 0xF, 0xF, true));
}
__device__ __forceinline__ float dpp_q1(float v) {
    return __int_as_float(__builtin_amdgcn_mov_dpp(__float_as_int(v), 0x55, 0xF, 0xF, true));
}
__device__ __forceinline__ float dpp_q2(float v) {
    return __int_as_float(__builtin_amdgcn_mov_dpp(__float_as_int(v), 0xAA, 0xF, 0xF, true));
}
__device__ __forceinline__ float dpp_q3(float v) {
    return __int_as_float(__builtin_amdgcn_mov_dpp(__float_as_int(v), 0xFF, 0xF, 0xF, true));
}
__device__ __forceinline__ v2f mk2(float x, float y) { v2f r; r.x = x; r.y = y; return r; }
__device__ __forceinline__ v2f pk_mul(v2f a, v2f b) {
    v2f d; asm("v_pk_mul_f32 %0, %1, %2" : "=v"(d) : "v"(a), "v"(b)); return d;
}
__device__ __forceinline__ v2f pk_fma(v2f a, v2f b, v2f c) {
    v2f d; asm("v_pk_fma_f32 %0, %1, %2, %3" : "=v"(d) : "v"(a), "v"(b), "v"(c)); return d;
}

// ============ Kernel 1: xproj[b][t][g*8+q] = x[t][b]·W_g[q][:128] + bias_g[q] ============
// (unchanged from R7, proven correct)
__launch_bounds__(256)
__global__ void qlstm_xproj(const float* __restrict__ x,
    const float* __restrict__ Wf, const float* __restrict__ bf,
    const float* __restrict__ Wi, const float* __restrict__ bi,
    const float* __restrict__ Wg, const float* __restrict__ bg,
    const float* __restrict__ Wo, const float* __restrict__ bo,
    float* __restrict__ xproj)
{
    const int b = blockIdx.x;
    const int wv = threadIdx.x >> 6;
    const int lane = threadIdx.x & 63;
    const int q = lane >> 3;
    const int kg = lane & 7;

    const float* Ws[4] = { Wf, Wi, Wg, Wo };
    const float* bs[4] = { bf, bi, bg, bo };
    float4 wfrag[4][4];
    float bias_w[4];
    #pragma unroll
    for (int g = 0; g < 4; ++g) {
        const float* Wq = Ws[g] + q * CATDIM + kg * 16;
        #pragma unroll
        for (int c4 = 0; c4 < 4; ++c4) wfrag[g][c4] = *(const float4*)(Wq + c4 * 4);
        bias_w[g] = bs[g][q];
    }

    for (int t = wv; t < TS; t += 4) {
        const float* xr = x + ((size_t)t * BB + b) * INDIM + kg * 16;
        float4 x0 = *(const float4*)(xr);
        float4 x1 = *(const float4*)(xr + 4);
        float4 x2 = *(const float4*)(xr + 8);
        float4 x3 = *(const float4*)(xr + 12);
        float* outrow = xproj + ((size_t)b * TS + t) * 32;
        #pragma unroll
        for (int g = 0; g < 4; ++g) {
            float p =
                x0.x*wfrag[g][0].x + x0.y*wfrag[g][0].y + x0.z*wfrag[g][0].z + x0.w*wfrag[g][0].w +
                x1.x*wfrag[g][1].x + x1.y*wfrag[g][1].y + x1.z*wfrag[g][1].z + x1.w*wfrag[g][1].w +
                x2.x*wfrag[g][2].x + x2.y*wfrag[g][2].y + x2.z*wfrag[g][2].z + x2.w*wfrag[g][2].w +
                x3.x*wfrag[g][3].x + x3.y*wfrag[g][3].y + x3.z*wfrag[g][3].z + x3.w*wfrag[g][3].w;
            p += dpp_xor1(p);
            p += dpp_xor2(p);
            p += __shfl_xor(p, 4, 64);
            if (kg == 0) outrow[g * 8 + q] = p + bias_w[g];
        }
    }
}

// ============ Kernel 2: transfer-matrix recurrence. Lane = (element, gate). ============
// Quantum circuit per gate collapses to an 8-wire chain over hermitian state
// (d0, d1, z): per wire w (full angles a_w, P0_w=layer0, P1_w=layer1):
//   gr=0.5*sinP0*cos(a), gi=-0.5*sin(a), AmB=cosP0*cos(a)
//   E_{w-1} = (d0+d1) + 4*gr*zr            (before transfer w; E_7 after wire7)
//   transfer: d0' = C*(0.5*u + 2*(p-q)), d1' = -C*(0.5*u2 + 2*(p+q)),
//             z'  = -S*(gr*(d0+d1)+zr, gi*(d0-d1)+AmB*zi),  C=cosP1, S=sinP1
// Derived from MPS form of gray-coded product state; verified on hand cases.
__launch_bounds__(64, 1)
__global__ void qlstm_tm(const float* __restrict__ xproj,
    const float* __restrict__ Wf, const float* __restrict__ Pf,
    const float* __restrict__ Wi, const float* __restrict__ Pi,
    const float* __restrict__ Wg, const float* __restrict__ Pg,
    const float* __restrict__ Wo, const float* __restrict__ Po,
    float* __restrict__ out, float* __restrict__ hst, float* __restrict__ cst)
{
    const int lane = threadIdx.x;
    const int g = lane & 3;
    const int el = lane >> 2;
    const int b = blockIdx.x * 16 + el;

    const float* W; const float* P;
    if (g == 0)      { W = Wf; P = Pf; }
    else if (g == 1) { W = Wi; P = Pi; }
    else if (g == 2) { W = Wg; P = Pg; }
    else             { W = Wo; P = Po; }

    // ---- per-wire trig constants (full angles, once) ----
    float hsp0[8], cp0c[8], Cw[8], Sw[8];
    #pragma unroll
    for (int w = 0; w < 8; ++w) {
        float s0, c0, s1, c1;
        __sincosf(P[w], &s0, &c0);
        __sincosf(P[8 + w], &s1, &c1);
        hsp0[w] = 0.5f * s0;
        cp0c[w] = c0;
        Cw[w] = c1;
        Sw[w] = s1;
    }

    // ---- h-weights for all 8 qubits of this lane's gate (packed pairs) ----
    v2f whp[8][4];
    #pragma unroll
    for (int q = 0; q < 8; ++q) {
        const float* Wq = W + q * CATDIM + INDIM;
        float4 wa = *(const float4*)(Wq);
        float4 wb = *(const float4*)(Wq + 4);
        whp[q][0] = mk2(wa.x, wa.y); whp[q][1] = mk2(wa.z, wa.w);
        whp[q][2] = mk2(wb.x, wb.y); whp[q][3] = mk2(wb.z, wb.w);
    }

    // activation map: act = (Aa*y + Bb)/(y+1), y = exp(kk*E)
    const float kk = (g == 2) ? 2.f : -1.f;
    const float Aa = (g == 2) ? 1.f : 0.f;
    const float Bb = (g == 2) ? -1.f : 1.f;

    float c_st[8], h_st[8];
    #pragma unroll
    for (int q = 0; q < 8; ++q) { c_st[q] = 0.f; h_st[q] = 0.f; }

    // xb prefetch for t=0
    const float* xbase = xproj + ((size_t)b * TS) * 32 + g * 8;
    float4 xv0 = *(const float4*)(xbase);
    float4 xv1 = *(const float4*)(xbase + 4);

    for (int t = 0; t < TS; ++t) {
        float xb[8] = { xv0.x, xv0.y, xv0.z, xv0.w, xv1.x, xv1.y, xv1.z, xv1.w };

        // prefetch t+1
        {
            int tn = (t + 1 < TS) ? t + 1 : t;
            const float* xr = xbase + (size_t)tn * 32;
            xv0 = *(const float4*)(xr);
            xv1 = *(const float4*)(xr + 4);
        }

        // ---- angles + full-angle sincos, all 8 wires ----
        v2f hp0 = mk2(h_st[0], h_st[1]), hp1 = mk2(h_st[2], h_st[3]);
        v2f hp2 = mk2(h_st[4], h_st[5]), hp3 = mk2(h_st[6], h_st[7]);
        float sa[8], ca[8];
        #pragma unroll
        for (int q = 0; q < 8; ++q) {
            v2f acc = pk_mul(hp0, whp[q][0]);
            acc = pk_fma(hp1, whp[q][1], acc);
            acc = pk_fma(hp2, whp[q][2], acc);
            acc = pk_fma(hp3, whp[q][3], acc);
            float ang = xb[q] + acc.x + acc.y;
            __sincosf(ang, &sa[q], &ca[q]);
        }

        // ---- transfer chain ----
        float E[8];
        float d0, d1, zr, zi;
        {   // wire 0 init: sigma = K0 .* (psi psi*)
            float gr = hsp0[0] * ca[0];
            float gi = -0.5f * sa[0];
            float AmB = cp0c[0] * ca[0];
            float A = 0.5f + 0.5f * AmB;
            d0 = Cw[0] * A;
            d1 = -Cw[0] * (1.f - A);
            zr = -Sw[0] * gr;
            zi = -Sw[0] * gi;
        }
        #pragma unroll
        for (int w = 1; w < 8; ++w) {
            float gr = hsp0[w] * ca[w];
            float gi = -0.5f * sa[w];
            float AmB = cp0c[w] * ca[w];
            float sum = d0 + d1, dif = d0 - d1;
            float p = gr * zr, qv = gi * zi;
            E[w - 1] = fmaf(4.f, p, sum);                 // E_{w-1} via first-I-wire weight
            float u  = fmaf(AmB, dif, sum);
            float u2 = fmaf(-AmB, dif, sum);
            float t0 = fmaf(2.f, p - qv, 0.5f * u);
            float t1 = fmaf(2.f, p + qv, 0.5f * u2);
            float nzr = -Sw[w] * fmaf(gr, sum, zr);
            float nzi = -Sw[w] * fmaf(AmB, zi, gi * dif);
            d0 = Cw[w] * t0;
            d1 = -Cw[w] * t1;
            zr = nzr; zi = nzi;
        }
        E[7] = (d0 + d1) + 2.f * zr;                      // full sum, no I-tail

        // ---- activations (branch-free, gate-uniform constants) ----
        float act[8];
        #pragma unroll
        for (int q = 0; q < 8; ++q) {
            float y = __expf(kk * E[q]);
            act[q] = fmaf(Aa, y, Bb) / (y + 1.f);
        }

        // ---- LSTM update: gather 4 gates across the quad, lane-local math ----
        #pragma unroll
        for (int q = 0; q < 8; ++q) {
            float fv = dpp_q0(act[q]);
            float iv = dpp_q1(act[q]);
            float gv = dpp_q2(act[q]);
            float ov = dpp_q3(act[q]);
            c_st[q] = fmaf(fv, c_st[q], iv * gv);
            float e2 = __expf(2.f * c_st[q]);
            float th = (e2 - 1.f) / (e2 + 1.f);
            h_st[q] = ov * th;
        }

        if (g == 0) {
            float* orow = out + ((size_t)t * BB + b) * NQ;
            #pragma unroll
            for (int q = 0; q < 8; ++q) orow[q] = h_st[q];
        }
    }

    if (g == 0) {
        #pragma unroll
        for (int q = 0; q < 8; ++q) {
            hst[b * NQ + q] = h_st[q];
            cst[b * NQ + q] = c_st[q];
        }
    }
}

extern "C" void kernel_launch(void* const* d_in, const int* in_sizes, int n_in,
                              void* d_out, int out_size, void* d_ws, size_t ws_size,
                              hipStream_t stream) {
    const float* x  = (const float*)d_in[0];
    const float* Wf = (const float*)d_in[1];
    const float* bf = (const float*)d_in[2];
    const float* Pf = (const float*)d_in[3];
    const float* Wi = (const float*)d_in[4];
    const float* bi = (const float*)d_in[5];
    const float* Pi = (const float*)d_in[6];
    const float* Wg = (const float*)d_in[7];
    const float* bg = (const float*)d_in[8];
    const float* Pg = (const float*)d_in[9];
    const float* Wo = (const float*)d_in[10];
    const float* bo = (const float*)d_in[11];
    const float* Po = (const float*)d_in[12];

    float* out = (float*)d_out;
    float* hst = out + (size_t)TS * BB * NQ;
    float* cst = hst + (size_t)BB * NQ;
    float* xproj = (float*)d_ws;             // TS*BB*32 floats = 33.5 MB scratch

    qlstm_xproj<<<BB, 256, 0, stream>>>(x, Wf, bf, Wi, bi, Wg, bg, Wo, bo, xproj);
    qlstm_tm<<<BB / 16, 64, 0, stream>>>(xproj, Wf, Pf, Wi, Pi, Wg, Pg, Wo, Po,
                                         out, hst, cst);
}

// Round 10
// 293.604 us; speedup vs baseline: 3.9183x; 1.2194x over previous
//
#include <hip/hip_runtime.h>
#include <math.h>

#define TS 256
#define BB 1024
#define NQ 8
#define INDIM 128
#define CATDIM 136

typedef float v2f __attribute__((ext_vector_type(2)));

__device__ __forceinline__ float dpp_xor1(float v) {
    return __int_as_float(__builtin_amdgcn_mov_dpp(__float_as_int(v), 0xB1, 0xF, 0xF, true));
}
__device__ __forceinline__ float dpp_xor2(float v) {
    return __int_as_float(__builtin_amdgcn_mov_dpp(__float_as_int(v), 0x4E, 0xF, 0xF, true));
}
__device__ __forceinline__ float dpp_xor8(float v) {   // row_ror:8 within 16 = lane^8
    return __int_as_float(__builtin_amdgcn_mov_dpp(__float_as_int(v), 0x128, 0xF, 0xF, true));
}
__device__ __forceinline__ float swz_xor16(float v) {  // ds_swizzle BitMode xor 16
    return __int_as_float(__builtin_amdgcn_ds_swizzle(__float_as_int(v), 0x401F));
}
__device__ __forceinline__ v2f mk2(float x, float y) { v2f r; r.x = x; r.y = y; return r; }

// ============ Kernel 1: xproj[b][t][g*8+q] = x[t][b]·W_g[q][:128] + bias_g[q] ============
// (unchanged from R7/R9, proven correct)
__launch_bounds__(256)
__global__ void qlstm_xproj(const float* __restrict__ x,
    const float* __restrict__ Wf, const float* __restrict__ bf,
    const float* __restrict__ Wi, const float* __restrict__ bi,
    const float* __restrict__ Wg, const float* __restrict__ bg,
    const float* __restrict__ Wo, const float* __restrict__ bo,
    float* __restrict__ xproj)
{
    const int b = blockIdx.x;
    const int wv = threadIdx.x >> 6;
    const int lane = threadIdx.x & 63;
    const int q = lane >> 3;
    const int kg = lane & 7;

    const float* Ws[4] = { Wf, Wi, Wg, Wo };
    const float* bs[4] = { bf, bi, bg, bo };
    float4 wfrag[4][4];
    float bias_w[4];
    #pragma unroll
    for (int g = 0; g < 4; ++g) {
        const float* Wq = Ws[g] + q * CATDIM + kg * 16;
        #pragma unroll
        for (int c4 = 0; c4 < 4; ++c4) wfrag[g][c4] = *(const float4*)(Wq + c4 * 4);
        bias_w[g] = bs[g][q];
    }

    for (int t = wv; t < TS; t += 4) {
        const float* xr = x + ((size_t)t * BB + b) * INDIM + kg * 16;
        float4 x0 = *(const float4*)(xr);
        float4 x1 = *(const float4*)(xr + 4);
        float4 x2 = *(const float4*)(xr + 8);
        float4 x3 = *(const float4*)(xr + 12);
        float* outrow = xproj + ((size_t)b * TS + t) * 32;
        #pragma unroll
        for (int g = 0; g < 4; ++g) {
            float p =
                x0.x*wfrag[g][0].x + x0.y*wfrag[g][0].y + x0.z*wfrag[g][0].z + x0.w*wfrag[g][0].w +
                x1.x*wfrag[g][1].x + x1.y*wfrag[g][1].y + x1.z*wfrag[g][1].z + x1.w*wfrag[g][1].w +
                x2.x*wfrag[g][2].x + x2.y*wfrag[g][2].y + x2.z*wfrag[g][2].z + x2.w*wfrag[g][2].w +
                x3.x*wfrag[g][3].x + x3.y*wfrag[g][3].y + x3.z*wfrag[g][3].z + x3.w*wfrag[g][3].w;
            p += dpp_xor1(p);
            p += dpp_xor2(p);
            p += __shfl_xor(p, 4, 64);
            if (kg == 0) outrow[g * 8 + q] = p + bias_w[g];
        }
    }
}

// ============ Kernel 2: q-split transfer-matrix recurrence ============
// Lane = (el2, g, q): lane = el2*32 + g*8 + q. One wave per block (no barriers;
// DS ops are in-order within a wave). Each lane: own-qubit angle + sincos +
// wire build; 8-lane group shares wires via LDS (write b128, 8 broadcast reads);
// serial 8-wire chain (R9's verified formulas) redundant per lane; own-qubit E
// selected in-flight; acts gathered across gates via dpp row_ror:8 + ds_swizzle
// xor16; h returns via 16-float LDS buffer.
__launch_bounds__(64, 1)
__global__ void qlstm_q(const float* __restrict__ xproj,
    const float* __restrict__ Wf, const float* __restrict__ Pf,
    const float* __restrict__ Wi, const float* __restrict__ Pi,
    const float* __restrict__ Wg, const float* __restrict__ Pg,
    const float* __restrict__ Wo, const float* __restrict__ Po,
    float* __restrict__ out, float* __restrict__ hst, float* __restrict__ cst)
{
    const int lane = threadIdx.x;
    const int q = lane & 7;
    const int g = (lane >> 3) & 3;
    const int el2 = lane >> 5;
    const int b = blockIdx.x * 2 + el2;

    __shared__ float hlds[16];
    __shared__ __align__(16) float4 wlds[64];

    const float* W; const float* P;
    if (g == 0)      { W = Wf; P = Pf; }
    else if (g == 1) { W = Wi; P = Pi; }
    else if (g == 2) { W = Wg; P = Pg; }
    else             { W = Wo; P = Po; }

    // ---- loop-invariant constants ----
    float Cw[8], Sw[8];
    #pragma unroll
    for (int w = 0; w < 8; ++w) {
        float s1, c1;
        __sincosf(P[8 + w], &s1, &c1);
        Cw[w] = c1; Sw[w] = s1;
    }
    float hsp0q, cp0cq;
    {
        float s0, c0;
        __sincosf(P[q], &s0, &c0);
        hsp0q = 0.5f * s0;
        cp0cq = c0;
    }
    // own-qubit h weights
    float wh[8];
    {
        const float* Wq = W + q * CATDIM + INDIM;
        #pragma unroll
        for (int j = 0; j < 8; ++j) wh[j] = Wq[j];
    }
    // activation constants: act = (Aa*y + Bb)/(y+1), y = exp(kk*E)
    const float kk = (g == 2) ? 2.f : -1.f;
    const float Aa = (g == 2) ? 1.f : 0.f;
    const float Bb = (g == 2) ? -1.f : 1.f;

    if (lane < 16) hlds[lane] = 0.f;   // single wave: DS in-order, no barrier

    float c_own = 0.f;
    float hv = 0.f;

    const float* xbase = xproj + ((size_t)b * TS) * 32 + (g * 8 + q);
    float xb = xbase[0];

    for (int t = 0; t < TS; ++t) {
        // ---- angle: own qubit ----
        float4 h01 = *(const float4*)&hlds[el2 * 8];
        float4 h23 = *(const float4*)&hlds[el2 * 8 + 4];
        float ang = xb
            + wh[0]*h01.x + wh[1]*h01.y + wh[2]*h01.z + wh[3]*h01.w
            + wh[4]*h23.x + wh[5]*h23.y + wh[6]*h23.z + wh[7]*h23.w;

        // prefetch next xb
        {
            int tn = (t + 1 < TS) ? t + 1 : t;
            xb = xbase[(size_t)tn * 32];
        }

        float sa, ca;
        __sincosf(ang, &sa, &ca);

        // ---- own wire quantities -> LDS ----
        float4 wq;
        wq.x = hsp0q * ca;          // gr
        wq.y = -0.5f * sa;          // gi
        wq.z = cp0cq * ca;          // AmB
        wq.w = 0.f;
        wlds[lane] = wq;

        // ---- read all 8 wires of this group (broadcast within group) ----
        const float4* gbase = &wlds[lane & 56];
        float4 wv[8];
        #pragma unroll
        for (int w = 0; w < 8; ++w) wv[w] = gbase[w];

        // ---- serial transfer chain (R9 verified), selecting own E ----
        float myE = 0.f;
        float d0, d1, zr, zi;
        {
            float A = 0.5f + 0.5f * wv[0].z;
            d0 = Cw[0] * A;
            d1 = -Cw[0] * (1.f - A);
            zr = -Sw[0] * wv[0].x;
            zi = -Sw[0] * wv[0].y;
        }
        #pragma unroll
        for (int w = 1; w < 8; ++w) {
            float gr = wv[w].x, gi = wv[w].y, AmB = wv[w].z;
            float sum = d0 + d1, dif = d0 - d1;
            float p = gr * zr, qv = gi * zi;
            float Ew = fmaf(4.f, p, sum);
            if (q == w - 1) myE = Ew;
            float u  = fmaf(AmB, dif, sum);
            float u2 = fmaf(-AmB, dif, sum);
            float t0 = fmaf(2.f, p - qv, 0.5f * u);
            float t1 = fmaf(2.f, p + qv, 0.5f * u2);
            float nzr = -Sw[w] * fmaf(gr, sum, zr);
            float nzi = -Sw[w] * fmaf(AmB, zi, gi * dif);
            d0 = Cw[w] * t0;
            d1 = -Cw[w] * t1;
            zr = nzr; zi = nzi;
        }
        {
            float E7 = (d0 + d1) + 2.f * zr;
            if (q == 7) myE = E7;
        }

        // ---- own activation ----
        float y = __expf(kk * myE);
        float a = fmaf(Aa, y, Bb) / (y + 1.f);

        // ---- gather 4 gates' activations for own qubit ----
        float a8 = dpp_xor8(a);                       // gate g^1
        v2f pA = (g & 1) ? mk2(a8, a) : mk2(a, a8);   // (f,i) or (g~,o)
        float pBx = swz_xor16(pA.x);                  // other pair
        float pBy = swz_xor16(pA.y);
        bool glo = (g & 2) == 0;
        float fv = glo ? pA.x : pBx;
        float iv = glo ? pA.y : pBy;
        float gv = glo ? pBx : pA.x;
        float ov = glo ? pBy : pA.y;

        // ---- lane-local LSTM (replicated across g, deterministic) ----
        c_own = fmaf(fv, c_own, iv * gv);
        float e2 = __expf(2.f * c_own);
        hv = ov * ((e2 - 1.f) / (e2 + 1.f));

        // ---- publish h (g==0 lanes) + output ----
        if ((lane & 24) == 0) {
            hlds[el2 * 8 + q] = hv;
            out[((size_t)t * BB + b) * NQ + q] = hv;
        }
    }

    if ((lane & 24) == 0) {
        hst[b * NQ + q] = hv;
        cst[b * NQ + q] = c_own;
    }
}

extern "C" void kernel_launch(void* const* d_in, const int* in_sizes, int n_in,
                              void* d_out, int out_size, void* d_ws, size_t ws_size,
                              hipStream_t stream) {
    const float* x  = (const float*)d_in[0];
    const float* Wf = (const float*)d_in[1];
    const float* bf = (const float*)d_in[2];
    const float* Pf = (const float*)d_in[3];
    const float* Wi = (const float*)d_in[4];
    const float* bi = (const float*)d_in[5];
    const float* Pi = (const float*)d_in[6];
    const float* Wg = (const float*)d_in[7];
    const float* bg = (const float*)d_in[8];
    const float* Pg = (const float*)d_in[9];
    const float* Wo = (const float*)d_in[10];
    const float* bo = (const float*)d_in[11];
    const float* Po = (const float*)d_in[12];

    float* out = (float*)d_out;
    float* hst = out + (size_t)TS * BB * NQ;
    float* cst = hst + (size_t)BB * NQ;
    float* xproj = (float*)d_ws;             // TS*BB*32 floats = 33.5 MB scratch

    qlstm_xproj<<<BB, 256, 0, stream>>>(x, Wf, bf, Wi, bi, Wg, bg, Wo, bo, xproj);
    qlstm_q<<<BB / 2, 64, 0, stream>>>(xproj, Wf, Pf, Wi, Pi, Wg, Pg, Wo, Po,
                                       out, hst, cst);
}